// Round 4
// baseline (4548.788 us; speedup 1.0000x reference)
//
#include <hip/hip_runtime.h>

#define BATCH 128
#define SEQ   512
#define EMB   512
#define HID   1024
#define NCLS  1000
#define NBLK  256    // 8 row groups x 32 blocks -> all 256 CUs
#define TPB   256    // 4 waves = 4 col groups per block

using short8 = __attribute__((ext_vector_type(8))) short;
using f32x4  = __attribute__((ext_vector_type(4))) float;
typedef unsigned long long u64;
using u64x2 = __attribute__((ext_vector_type(2))) unsigned long long;

__device__ __forceinline__ short f2bf(float f) {
    unsigned u = __float_as_uint(f);
    unsigned r = (u + 0x7fffu + ((u >> 16) & 1u)) >> 16;   // RNE
    return (short)r;
}
__device__ __forceinline__ float bf2f(short s) {
    unsigned u = ((unsigned)(unsigned short)s) << 16;
    return __uint_as_float(u);
}

// ---- ws layout (bytes) ----
#define OFF_CH0 0u
#define OFF_CL0 (256u << 10)
#define OFF_FLG (512u << 10)          // 256 flags, 64B apart (16 KB)
#define OFF_CH1 (528u << 10)
#define OFF_CL1 (784u << 10)
#define OFF_H   (1040u << 10)
#define ZERO_I4 33792u                // first 528 KB zeroed (ch0, cl0, flags)

__global__ void mgu_init(int4* __restrict__ ws4) {
    unsigned i = blockIdx.x * blockDim.x + threadIdx.x;
    if (i < ZERO_I4) ws4[i] = make_int4(0, 0, 0, 0);
}

// ---------------- sequential scan ----------------
// 256 blocks x 256 threads. Block b: row group rg = b>>5 (16 batch rows),
// wave w: gate-cols j0 = ((b&31)*4+w)*8 (z in lanes n<8, h~ in n>=8).
// Weights resident in registers (48 x short8/lane). h state in registers.
// A staged in LDS in FRAGMENT-LINEAR layout: slot s=ks*64+lane holds
// A[row=lane&15][k=ks*32+(lane>>4)*8 ..+7] at byte s*16 -> ds_read_b128 and
// staging writes are lane-linear => zero bank conflicts.
// Cross-block exchange via relaxed AGENT-scope atomics (coherence point = LLC);
// per-producer monotonic flags replace the atomicAdd barrier.
__global__ __launch_bounds__(TPB, 1) void mgu_scan(
    const int* __restrict__ x, const float* __restrict__ emb,
    const float* __restrict__ Wz, const float* __restrict__ bz,
    const float* __restrict__ Wh, const float* __restrict__ bh,
    short* __restrict__ ch0, short* __restrict__ cl0,
    short* __restrict__ ch1, short* __restrict__ cl1,
    unsigned* __restrict__ flags, float* __restrict__ h)
{
    __shared__ short As[48 * 64 * 8];          // 48 KB: hi fragments (emb ks 0..15, h ks 16..47)
    __shared__ short Al[32 * 64 * 8 + 2048];   // 32 KB + 4 KB pad -> 84 KB total: 1 block/CU

    const int tid  = threadIdx.x;
    const int w    = tid >> 6;                 // wave 0..3
    const int lane = tid & 63;
    const int q    = lane >> 4;
    const int n    = lane & 15;
    const int blk  = blockIdx.x;
    const int rg   = blk >> 5;
    const int r0   = rg << 4;
    const int pb   = blk & 31;                 // producer index within row group
    const int j0   = (((blk & 31) << 2) + w) << 3;

    // ---- persistent weight fragments (B-frag: B[k=q*8+i][col=lane&15]) ----
    const float* Wg = (n < 8) ? Wz : Wh;
    const float* wp = Wg + j0 + (n & 7);
    short8 Bf[48];
#pragma unroll
    for (int ks = 0; ks < 48; ++ks) {
        short8 f;
#pragma unroll
        for (int i = 0; i < 8; ++i)
            f[i] = f2bf(wp[(long)(ks * 32 + q * 8 + i) * HID]);
        Bf[ks] = f;
    }
    const float bzv = bz[j0 + (n & 7)];
    const float bhv = bh[j0 + (n & 7)];

    float hreg[4] = {0.f, 0.f, 0.f, 0.f};      // lanes n<8: rows r0+q*4+r2, col j0+n

    auto stage_emb = [&](int tt) {             // fragment slots 0..1023 (ks 0..15)
#pragma unroll
        for (int i = 0; i < 4; ++i) {
            int s  = tid + (i << 8);
            int nn = s & 15, qq = (s >> 4) & 3, ks = s >> 6;
            int tok = x[(r0 + nn) * SEQ + tt];
            const float4* ep = (const float4*)(emb + (long)tok * EMB + ks * 32 + qq * 8);
            float4 e0 = ep[0], e1 = ep[1];
            short8 v;
            v[0] = f2bf(e0.x); v[1] = f2bf(e0.y); v[2] = f2bf(e0.z); v[3] = f2bf(e0.w);
            v[4] = f2bf(e1.x); v[5] = f2bf(e1.y); v[6] = f2bf(e1.z); v[7] = f2bf(e1.w);
            *(short8*)&As[s * 8] = v;
        }
    };

    stage_emb(0);

    for (int t = 0; t < SEQ; ++t) {
        const short* chR = (t & 1) ? ch1 : ch0;
        const short* clR = (t & 1) ? cl1 : cl0;
        short*       chW = (t & 1) ? ch0 : ch1;
        short*       clW = (t & 1) ? cl0 : cl1;

        // ---- wait for peers' step-t data (flags monotonic, no reset) ----
        if (t > 0 && w == 0) {
            const unsigned* fp = flags + (((rg << 5) + (lane & 31)) << 4);  // 64B spacing
            const unsigned tgt = (unsigned)t;
            for (;;) {
                unsigned f = __hip_atomic_load(fp, __ATOMIC_RELAXED, __HIP_MEMORY_SCOPE_AGENT);
                if (!__ballot((lane < 32) && (f < tgt))) break;
                __builtin_amdgcn_s_sleep(1);
            }
        }
        __syncthreads();

        // ---- stage h hi (slots 1024..3071) and lo (slots 0..2047) ----
        u64 hv[16], lv[16];
#pragma unroll
        for (int i = 0; i < 8; ++i) {
            int s  = 1024 + tid + (i << 8);
            int nn = s & 15, qq = (s >> 4) & 3, ks = s >> 6;          // ks 16..47
            const u64* gp = (const u64*)(chR + (r0 + nn) * HID + (ks * 32 + qq * 8 - 512));
            hv[2 * i]     = __hip_atomic_load(gp,     __ATOMIC_RELAXED, __HIP_MEMORY_SCOPE_AGENT);
            hv[2 * i + 1] = __hip_atomic_load(gp + 1, __ATOMIC_RELAXED, __HIP_MEMORY_SCOPE_AGENT);
        }
#pragma unroll
        for (int i = 0; i < 8; ++i) {
            int s  = tid + (i << 8);
            int nn = s & 15, qq = (s >> 4) & 3, ks = s >> 6;          // ks 0..31
            const u64* gp = (const u64*)(clR + (r0 + nn) * HID + (ks * 32 + qq * 8));
            lv[2 * i]     = __hip_atomic_load(gp,     __ATOMIC_RELAXED, __HIP_MEMORY_SCOPE_AGENT);
            lv[2 * i + 1] = __hip_atomic_load(gp + 1, __ATOMIC_RELAXED, __HIP_MEMORY_SCOPE_AGENT);
        }
#pragma unroll
        for (int i = 0; i < 8; ++i) {
            int s = 1024 + tid + (i << 8);
            u64x2 v; v[0] = hv[2 * i]; v[1] = hv[2 * i + 1];
            *(u64x2*)&As[s * 8] = v;                                  // 16B linear writes
        }
#pragma unroll
        for (int i = 0; i < 8; ++i) {
            int s = tid + (i << 8);
            u64x2 v; v[0] = lv[2 * i]; v[1] = lv[2 * i + 1];
            *(u64x2*)&Al[s * 8] = v;
        }
        __syncthreads();

        // ---- MFMA: A-fragments lane-linear from LDS, B resident ----
        const short* ap  = &As[lane * 8];      // + ks*512 shorts (1024 B) per k-step
        const short* alp = &Al[lane * 8];
        f32x4 a0 = {0.f,0.f,0.f,0.f}, a1 = a0, a2 = a0, a3 = a0;
#pragma unroll
        for (int ks = 0; ks < 48; ks += 4) {
            short8 f0 = *(const short8*)(ap + (ks + 0) * 512);
            short8 f1 = *(const short8*)(ap + (ks + 1) * 512);
            short8 f2 = *(const short8*)(ap + (ks + 2) * 512);
            short8 f3 = *(const short8*)(ap + (ks + 3) * 512);
            a0 = __builtin_amdgcn_mfma_f32_16x16x32_bf16(f0, Bf[ks + 0], a0, 0, 0, 0);
            a1 = __builtin_amdgcn_mfma_f32_16x16x32_bf16(f1, Bf[ks + 1], a1, 0, 0, 0);
            a2 = __builtin_amdgcn_mfma_f32_16x16x32_bf16(f2, Bf[ks + 2], a2, 0, 0, 0);
            a3 = __builtin_amdgcn_mfma_f32_16x16x32_bf16(f3, Bf[ks + 3], a3, 0, 0, 0);
        }
#pragma unroll
        for (int e = 0; e < 32; e += 4) {      // lo correction reuses Bf[16..47]
            short8 g0 = *(const short8*)(alp + (e + 0) * 512);
            short8 g1 = *(const short8*)(alp + (e + 1) * 512);
            short8 g2 = *(const short8*)(alp + (e + 2) * 512);
            short8 g3 = *(const short8*)(alp + (e + 3) * 512);
            a0 = __builtin_amdgcn_mfma_f32_16x16x32_bf16(g0, Bf[16 + e + 0], a0, 0, 0, 0);
            a1 = __builtin_amdgcn_mfma_f32_16x16x32_bf16(g1, Bf[16 + e + 1], a1, 0, 0, 0);
            a2 = __builtin_amdgcn_mfma_f32_16x16x32_bf16(g2, Bf[16 + e + 2], a2, 0, 0, 0);
            a3 = __builtin_amdgcn_mfma_f32_16x16x32_bf16(g3, Bf[16 + e + 3], a3, 0, 0, 0);
        }
        f32x4 acc = (a0 + a1) + (a2 + a3);

        // z-pre lanes n<8, h~-pre lanes n>=8 (same col); partner = lane^8
        float o0 = __shfl_xor(acc[0], 8, 64);
        float o1 = __shfl_xor(acc[1], 8, 64);
        float o2 = __shfl_xor(acc[2], 8, 64);
        float o3 = __shfl_xor(acc[3], 8, 64);

        if (n < 8) {
            float zp[4] = {acc[0], acc[1], acc[2], acc[3]};
            float tp[4] = {o0, o1, o2, o3};
            const int j = j0 + n;
#pragma unroll
            for (int r2 = 0; r2 < 4; ++r2) {
                float z  = 1.f / (1.f + __expf(-(zp[r2] + bzv)));
                float ht = tanhf(tp[r2] + bhv);
                float ho = hreg[r2];
                float hn = ho + z * (ht - ho);
                hreg[r2] = hn;
                int rr = (r0 + q * 4 + r2) * HID + j;
                if (t < SEQ - 1) {
                    short hi = f2bf(hn);
                    __hip_atomic_store(chW + rr, hi, __ATOMIC_RELAXED, __HIP_MEMORY_SCOPE_AGENT);
                    __hip_atomic_store(clW + rr, f2bf(hn - bf2f(hi)), __ATOMIC_RELAXED, __HIP_MEMORY_SCOPE_AGENT);
                } else {
                    h[rr] = hn;               // final fp32 state for FC
                }
            }
        }

        if (t < SEQ - 1) {
            __syncthreads();                   // drains each thread's vmcnt => data at LLC
            if (tid == 0)
                __hip_atomic_store(flags + (((rg << 5) + pb) << 4), (unsigned)(t + 1),
                                   __ATOMIC_RELAXED, __HIP_MEMORY_SCOPE_AGENT);
            stage_emb(t + 1);                  // overlap emb gather with peers' lag
        }
    }
}

// ---------------- final FC: logits = h @ Wfc + bfc, full fp32 ----------------
__global__ __launch_bounds__(256) void mgu_fc(const float* __restrict__ h,
                                              const float* __restrict__ Wfc,
                                              const float* __restrict__ bfc,
                                              float* __restrict__ out) {
    __shared__ float hs[BATCH][65];
    const int tid = threadIdx.x;
    const int n0  = blockIdx.x * 8;
    const int b   = tid & 127;
    const int nn  = tid >> 7;
    const int nc  = n0 + nn * 4;
    float acc0 = 0.f, acc1 = 0.f, acc2 = 0.f, acc3 = 0.f;

    for (int k0 = 0; k0 < HID; k0 += 64) {
        __syncthreads();
#pragma unroll
        for (int jj = 0; jj < 8; ++jj) {
            int idx = tid + jj * 256;
            int bb  = idx >> 4;
            int kk  = (idx & 15) << 2;
            const float4 v = *(const float4*)(h + bb * HID + k0 + kk);
            hs[bb][kk] = v.x; hs[bb][kk + 1] = v.y; hs[bb][kk + 2] = v.z; hs[bb][kk + 3] = v.w;
        }
        __syncthreads();
#pragma unroll 8
        for (int k = 0; k < 64; ++k) {
            float hv = hs[b][k];
            const float4 wv = *(const float4*)(Wfc + (long)(k0 + k) * NCLS + nc);
            acc0 += hv * wv.x; acc1 += hv * wv.y; acc2 += hv * wv.z; acc3 += hv * wv.w;
        }
    }
    float* op = out + b * NCLS + nc;
    op[0] = acc0 + bfc[nc + 0];
    op[1] = acc1 + bfc[nc + 1];
    op[2] = acc2 + bfc[nc + 2];
    op[3] = acc3 + bfc[nc + 3];
}

extern "C" void kernel_launch(void* const* d_in, const int* in_sizes, int n_in,
                              void* d_out, int out_size, void* d_ws, size_t ws_size,
                              hipStream_t stream) {
    const int*   x   = (const int*)  d_in[0];
    const float* emb = (const float*)d_in[1];
    const float* Wz  = (const float*)d_in[2];
    const float* bz  = (const float*)d_in[3];
    const float* Wh  = (const float*)d_in[4];
    const float* bh  = (const float*)d_in[5];
    const float* Wfc = (const float*)d_in[6];
    const float* bfc = (const float*)d_in[7];
    float* out = (float*)d_out;

    char* ws = (char*)d_ws;
    short*    ch0   = (short*)   (ws + OFF_CH0);
    short*    cl0   = (short*)   (ws + OFF_CL0);
    unsigned* flags = (unsigned*)(ws + OFF_FLG);
    short*    ch1   = (short*)   (ws + OFF_CH1);
    short*    cl1   = (short*)   (ws + OFF_CL1);
    float*    h     = (float*)   (ws + OFF_H);

    mgu_init<<<132, 256, 0, stream>>>((int4*)ws);   // zero ch0/cl0/flags

    mgu_scan<<<NBLK, TPB, 0, stream>>>(x, emb, Wz, bz, Wh, bh,
                                       ch0, cl0, ch1, cl1, flags, h);

    mgu_fc<<<125, 256, 0, stream>>>(h, Wfc, bfc, out);
}